// Round 19
// baseline (35.641 us; speedup 1.0000x reference)
//
#include <hip/hip_runtime.h>
#include <math.h>

#define BB 32
#define LL 512
#define DD 1024
#define TT 256
#define NK 136393              // kept (s,e) pairs per batch
#define NK_LIN 131273          // off(502)
#define S_LIN 502
#define NEG_BIG  -3.0e38f      // finite stand-in for -inf
#define NEG_MASK -1.0e30f      // finite stand-in for masked logits
#define P_TOT (BB * NK)        // 4364576 (multiple of 16)
#define SC4 (P_TOT / 4)        // 1091144 quads
#define SC16 (P_TOT / 16)      // 272786 64B lines
#define GEMV_BLOCKS (BB * LL / 4)            // 4096
#define NP2 ((NK + 1) / 2)                   // 68197 pattern pairs
#define BPG ((NP2 + 255) / 256)              // 267 chunks per batch-group
#define BND_BLOCKS (BPG * 2)                 // 534
#define GRID1 (512 * 9 + (BND_BLOCKS - 512)) // 4630 (8:1 stripe + 22 extra)
#define MS16_CNT ((SC16 + 255) / 256)        // 1066
#define TAILQ_CNT (BB * 8)                   // 256
#define GRID2 (MS16_CNT + TAILQ_CNT)         // 1322

typedef float f4v __attribute__((ext_vector_type(4)));
typedef float f2v __attribute__((ext_vector_type(2)));

__device__ __forceinline__ int off_s(int s) {
    return (s <= S_LIN) ? s * (s + 21) / 2 : NK_LIN + (s - S_LIN) * LL;
}
__device__ __forceinline__ void invert(int k, int& s, int& e) {
    if (k >= NK_LIN) {
        const int r = k - NK_LIN;
        s = S_LIN + (r >> 9);
        e = r & 511;
    } else {
        float f = sqrtf(8.0f * (float)k + 441.0f);
        s = (int)((f - 21.0f) * 0.5f);
        if (s < 0) s = 0;
        if (s > 501) s = 501;
        while ((s + 1) * (s + 22) / 2 <= k) ++s;
        while (s * (s + 21) / 2 > k) --s;
        e = k - s * (s + 21) / 2;
    }
}
__device__ __forceinline__ void adv(int& s, int& e) {
    const int rowlen = (s <= S_LIN) ? (s + 11) : LL;
    if (++e >= rowlen) { e = 0; ++s; }        // s may reach 512: caller guards
}

// ---- d1: [GEMV read stream (8) : bounds-paired write stream (1)] ---------
// Bounds now ride with the gemv: text reads are largely L3-served (R12/R13:
// FETCH 37-42MB < 64MB), leaving HBM write path free for the 35MB bounds.
__global__ __launch_bounds__(256) void gemv_bounds_kernel(
    const float* __restrict__ text, const float* __restrict__ W,
    const float* __restrict__ bias, const int* __restrict__ mask,
    float* __restrict__ slp, float* __restrict__ elp, float* __restrict__ mlp,
    float* __restrict__ out)
{
    const int id = blockIdx.x;
    const int t  = threadIdx.x;

    int bv = -1;
    int g  = -1;
    if (id < 512 * 9) {
        const int q = id / 9, r = id - q * 9;
        if (r == 8) bv = q; else g = q * 8 + r;
    } else {
        bv = 512 + (id - 512 * 9);
    }

    if (g >= 0) {
        // ---- GEMV: logits = text @ W + b, wave per row (measured-best) ----
        const int wid  = t >> 6;
        const int lane = t & 63;
        const int row  = g * 4 + wid;             // row = b*L + l
        const f4v* t4 = (const f4v*)(text + (size_t)row * DD);
        const f4v* w4 = (const f4v*)W;
        float a0 = 0.f, a1 = 0.f, a2 = 0.f;
#pragma unroll
        for (int j = 0; j < 4; ++j) {
            const int fi = lane + j * 64;
            f4v v  = t4[fi];                      // coalesced 1KB/instr/wave
            f4v w0 = w4[fi * 3 + 0];              // L1-hot
            f4v w1 = w4[fi * 3 + 1];
            f4v w2 = w4[fi * 3 + 2];
            a0 += v.x * w0.x;  a1 += v.x * w0.y;  a2 += v.x * w0.z;
            a0 += v.y * w0.w;  a1 += v.y * w1.x;  a2 += v.y * w1.y;
            a0 += v.z * w1.z;  a1 += v.z * w1.w;  a2 += v.z * w2.x;
            a0 += v.w * w2.y;  a1 += v.w * w2.z;  a2 += v.w * w2.w;
        }
#pragma unroll
        for (int o = 32; o; o >>= 1) {
            a0 += __shfl_down(a0, o);
            a1 += __shfl_down(a1, o);
            a2 += __shfl_down(a2, o);
        }
        if (lane == 0) {
            const int m = mask[row];
            slp[row] = (m == 1) ? a0 + bias[0] : NEG_MASK;
            elp[row] = (m == 1) ? a1 + bias[1] : NEG_MASK;
            mlp[row] = (m == 1) ? a2 + bias[2] : NEG_MASK;
        }
        return;
    }

    // ---- bounds: 2 pattern positions per thread, f4v stores, 16 batches --
    const int gg = (bv >= BPG) ? 1 : 0;           // batch group
    const int c  = bv - gg * BPG;
    const int pp = c * 256 + t;
    if (pp >= NP2) return;
    const int p0 = 2 * pp;
    int s0, e0; invert(p0, s0, e0);
    int s1 = s0, e1 = e0; adv(s1, e1);            // p0+1 (valid if p0+1<NK)
    int s2 = s1, e2 = e1; if (p0 + 2 < NK) adv(s2, e2);  // p0+2
    const float S0 = (float)s0, E0 = (float)e0;
    const float S1 = (float)s1, E1 = (float)e1;
    const float S2 = (float)s2, E2 = (float)e2;
    float* bp = out + (size_t)P_TOT;
#pragma unroll
    for (int j = 0; j < 16; ++j) {
        const int bb = gg * 16 + j;
        const size_t B = (size_t)bb * NK;
        if ((bb & 1) == 0) {                      // B even: (B+p0) even
            if (p0 + 1 < NK) {
                f4v vv = {S0, E0, S1, E1};
                *(f4v*)(bp + (B + p0) * 2) = vv;  // 16B aligned
            } else {
                f2v v2 = {S0, E0};
                *(f2v*)(bp + (B + p0) * 2) = v2;
            }
        } else {                                  // B odd: pairs (p0+1, p0+2)
            if (pp == 0) {                        // position 0: (s,e)=(0,0)
                f2v v2 = {0.f, 0.f};
                *(f2v*)(bp + B * 2) = v2;
            }
            if (p0 + 2 < NK) {
                f4v vv = {S1, E1, S2, E2};
                *(f4v*)(bp + (B + p0 + 1) * 2) = vv;  // (B+p0+1) even
            } else if (p0 + 1 < NK) {
                f2v v2 = {S1, E1};
                *(f2v*)(bp + (B + p0 + 1) * 2) = v2;
            }
        }
    }
}

// ---- d2: [memset 64B/thread (pure quads) | tailquad (R18 verbatim)] ------
__global__ __launch_bounds__(256) void emit_kernel(
    const float* __restrict__ slp, const float* __restrict__ elp,
    const float* __restrict__ mlp, const int* __restrict__ mask,
    const int* __restrict__ tmap, float* __restrict__ out)
{
    const int id = blockIdx.x;
    const int t  = threadIdx.x;

    if (id < MS16_CNT) {
        // ======== memset: 4 quads/thread; write PURE quads only ========
        const int gid = id * 256 + t;
        if (gid >= SC16) return;
        const int p16 = gid * 16;
        const int b = p16 / NK;                   // magic-mul
        const int k = p16 - b * NK;
        int s, e;
        invert(k, s, e);
        const f4v neg = {NEG_BIG, NEG_BIG, NEG_BIG, NEG_BIG};
        if (e + 15 < s) {                         // fast path (~90%)
            f4v* q = (f4v*)(out + p16);
            q[0] = neg; q[1] = neg; q[2] = neg; q[3] = neg;
            return;
        }
        int ss = s, ee = e;
        int rowlen = (ss <= S_LIN) ? (ss + 11) : LL;
#pragma unroll
        for (int qq = 0; qq < 4; ++qq) {
            bool pure = true;
#pragma unroll
            for (int kk = 0; kk < 4; ++kk) {
                if (ee >= ss) pure = false;
                ++ee;
                if (ee >= rowlen) {
                    ee = 0; ++ss;
                    if (ss >= LL) ss = 0;         // next batch row 0 (nonpure)
                    rowlen = (ss <= S_LIN) ? (ss + 11) : LL;
                }
            }
            if (pure) *(f4v*)(out + p16 + 4 * qq) = neg;
        }
        return;
    }

    // ======== tailquad: batch b, rows [r0, r0+64) (R18 verbatim) ========
    const int tq = id - MS16_CNT;
    const int b  = tq >> 3;
    const int r0 = (tq & 7) << 6;
    __shared__ float sl[LL], el[LL], ml[LL];
    __shared__ unsigned char fsb[LL], feb[LL];
    const int base = b * LL;
    const int i0 = t, i1 = t + 256;
    const int mk0 = mask[base + i0], mk1 = mask[base + i1];
    sl[i0] = slp[base + i0]; el[i0] = elp[base + i0]; ml[i0] = mlp[base + i0];
    sl[i1] = slp[base + i1]; el[i1] = elp[base + i1]; ml[i1] = mlp[base + i1];
    fsb[i0] = 0; fsb[i1] = 0; feb[i0] = 0; feb[i1] = 0;
    __syncthreads();
    {   // t in [0,256) == TT
        int s0 = tmap[((size_t)b * TT + t) * 2 + 0];
        int e0 = tmap[((size_t)b * TT + t) * 2 + 1] - 1;
        s0 = min(max(s0, 0), LL - 1);
        e0 = min(max(e0, 0), LL - 1);
        fsb[s0] = 1;                              // benign race: all write 1
        feb[e0] = 1;
    }
    __syncthreads();
    fsb[i0] = (i0 != 0 && fsb[i0] && mk0 == 1) ? 1 : 0;
    fsb[i1] = (fsb[i1] && mk1 == 1) ? 1 : 0;
    feb[i0] = (i0 != 0 && feb[i0]) ? 1 : 0;
    __syncthreads();

    for (int it = t; it < 64 * 5; it += 256) {
        const int s_loc = it / 5;
        const int slot  = it - s_loc * 5;         // 0..4
        const int s     = r0 + s_loc;
        const int offf  = b * NK + off_s(s);      // flat row start
        const int rowlen = (s <= S_LIN) ? (s + 11) : LL;
        const int p0 = ((((offf + s) >> 2) - 1 + slot) << 2);
        if (p0 < offf || p0 >= offf + rowlen) continue;   // not owner
        float vals[4];
        bool nonpure = false;
#pragma unroll
        for (int kk = 0; kk < 4; ++kk) {
            const int p = p0 + kk;
            float v = NEG_BIG;
            int rr, er;
            if (p < offf + rowlen) { rr = s;     er = p - offf; }
            else                   { rr = s + 1; er = p - offf - rowlen; }
            if (rr < LL) {
                if (er >= rr) {                   // tail position
                    nonpure = true;
                    if (fsb[rr] && feb[er]) {
                        float w = 0.f;
                        for (int l = rr; l <= er; ++l) w += ml[l];
                        v = sl[rr] + el[er] + w;
                        if (v < -1.0e29f) v = NEG_BIG;    // masked -> -inf
                    }
                }
            } else {
                nonpure = true;                   // next batch row 0: invalid
            }
            vals[kk] = v;
        }
        if (nonpure) {
            f4v vv = {vals[0], vals[1], vals[2], vals[3]};
            *(f4v*)(out + p0) = vv;
        }
    }
}

extern "C" void kernel_launch(void* const* d_in, const int* in_sizes, int n_in,
                              void* d_out, int out_size, void* d_ws, size_t ws_size,
                              hipStream_t stream) {
    const float* text = (const float*)d_in[0];   // (B,L,D) f32
    const int*   mask = (const int*)d_in[1];     // (B,L) i32
    const int*   tmap = (const int*)d_in[2];     // (B,T,2) i32
    const float* W    = (const float*)d_in[3];   // (D,3) f32
    const float* bias = (const float*)d_in[4];   // (3,) f32
    float* out = (float*)d_out;

    float* slp = (float*)d_ws;                   // B*L each
    float* elp = slp + (size_t)BB * LL;
    float* mlp = elp + (size_t)BB * LL;

    gemv_bounds_kernel<<<GRID1, 256, 0, stream>>>(text, W, bias, mask,
                                                  slp, elp, mlp, out);
    emit_kernel<<<GRID2, 256, 0, stream>>>(slp, elp, mlp, mask, tmap, out);
}

// Round 20
// 26.798 us; speedup vs baseline: 1.3300x; 1.3300x over previous
//
#include <hip/hip_runtime.h>
#include <math.h>

#define BB 32
#define LL 512
#define DD 1024
#define TT 256
#define NK 136393              // kept (s,e) pairs per batch
#define NK_LIN 131273          // off(502)
#define S_LIN 502
#define NEG_BIG  -3.0e38f      // finite stand-in for -inf
#define NEG_MASK -1.0e30f      // finite stand-in for masked logits
#define P_TOT (BB * NK)        // 4364576 (multiple of 4)
#define SC4 (P_TOT / 4)        // 1091144
#define GEMV_BLOCKS (BB * LL / 4)            // 4096
#define TAILQ_CNT (BB * 8)                   // 256 (8 per batch, 64 rows each)
#define MEMSET_CNT ((SC4 + 255) / 256)       // 4263
#define NP2 ((NK + 1) / 2)                   // 68197 pattern pairs
#define BPG ((NP2 + 255) / 256)              // 267 chunks per batch-group
#define BND_BLOCKS (BPG * 2)                 // 534
#define D2_BLOCKS (TAILQ_CNT + MEMSET_CNT + BND_BLOCKS)

typedef float f4v __attribute__((ext_vector_type(4)));
typedef float f2v __attribute__((ext_vector_type(2)));

__device__ __forceinline__ int off_s(int s) {
    return (s <= S_LIN) ? s * (s + 21) / 2 : NK_LIN + (s - S_LIN) * LL;
}
__device__ __forceinline__ void invert(int k, int& s, int& e) {
    if (k >= NK_LIN) {
        const int r = k - NK_LIN;
        s = S_LIN + (r >> 9);
        e = r & 511;
    } else {
        float f = sqrtf(8.0f * (float)k + 441.0f);
        s = (int)((f - 21.0f) * 0.5f);
        if (s < 0) s = 0;
        if (s > 501) s = 501;
        while ((s + 1) * (s + 22) / 2 <= k) ++s;
        while (s * (s + 21) / 2 > k) --s;
        e = k - s * (s + 21) / 2;
    }
}
__device__ __forceinline__ void adv(int& s, int& e) {
    const int rowlen = (s <= S_LIN) ? (s + 11) : LL;
    if (++e >= rowlen) { e = 0; ++s; }
}

// ---- d1: PURE READ stream: logits = text @ W + b, wave per row -----------
__global__ __launch_bounds__(256) void gemv_kernel(
    const float* __restrict__ text, const float* __restrict__ W,
    const float* __restrict__ bias, const int* __restrict__ mask,
    float* __restrict__ slp, float* __restrict__ elp, float* __restrict__ mlp)
{
    const int wid  = threadIdx.x >> 6;
    const int lane = threadIdx.x & 63;
    const int row  = blockIdx.x * 4 + wid;        // row = b*L + l
    const f4v* t4 = (const f4v*)(text + (size_t)row * DD);
    const f4v* w4 = (const f4v*)W;
    float a0 = 0.f, a1 = 0.f, a2 = 0.f;
#pragma unroll
    for (int j = 0; j < 4; ++j) {
        const int fi = lane + j * 64;
        f4v v  = t4[fi];                          // coalesced 1KB/instr/wave
        f4v w0 = w4[fi * 3 + 0];                  // L1-hot
        f4v w1 = w4[fi * 3 + 1];
        f4v w2 = w4[fi * 3 + 2];
        a0 += v.x * w0.x;  a1 += v.x * w0.y;  a2 += v.x * w0.z;
        a0 += v.y * w0.w;  a1 += v.y * w1.x;  a2 += v.y * w1.y;
        a0 += v.z * w1.z;  a1 += v.z * w1.w;  a2 += v.z * w2.x;
        a0 += v.w * w2.y;  a1 += v.w * w2.z;  a2 += v.w * w2.w;
    }
#pragma unroll
    for (int o = 32; o; o >>= 1) {
        a0 += __shfl_down(a0, o);
        a1 += __shfl_down(a1, o);
        a2 += __shfl_down(a2, o);
    }
    if (lane == 0) {
        const int m = mask[row];
        slp[row] = (m == 1) ? a0 + bias[0] : NEG_MASK;
        elp[row] = (m == 1) ? a1 + bias[1] : NEG_MASK;
        mlp[row] = (m == 1) ? a2 + bias[2] : NEG_MASK;
    }
}

// ---- d2: [tailquad | memset(pure quads) | bounds paired-f4v] -------------
// R18's proven structure; bounds upgraded to 16B paired stores (R19-validated).
__global__ __launch_bounds__(256) void emit_kernel(
    const float* __restrict__ slp, const float* __restrict__ elp,
    const float* __restrict__ mlp, const int* __restrict__ mask,
    const int* __restrict__ tmap, float* __restrict__ out)
{
    const int id = blockIdx.x;
    const int t  = threadIdx.x;

    if (id < TAILQ_CNT) {
        // ======== tailquad: batch b, rows [r0, r0+64) (R18 verbatim) ======
        const int b  = id >> 3;
        const int r0 = (id & 7) << 6;
        __shared__ float sl[LL], el[LL], ml[LL];
        __shared__ unsigned char fsb[LL], feb[LL];
        const int base = b * LL;
        const int i0 = t, i1 = t + 256;
        const int mk0 = mask[base + i0], mk1 = mask[base + i1];
        sl[i0] = slp[base + i0]; el[i0] = elp[base + i0]; ml[i0] = mlp[base + i0];
        sl[i1] = slp[base + i1]; el[i1] = elp[base + i1]; ml[i1] = mlp[base + i1];
        fsb[i0] = 0; fsb[i1] = 0; feb[i0] = 0; feb[i1] = 0;
        __syncthreads();
        {   // t in [0,256) == TT
            int s0 = tmap[((size_t)b * TT + t) * 2 + 0];
            int e0 = tmap[((size_t)b * TT + t) * 2 + 1] - 1;
            s0 = min(max(s0, 0), LL - 1);
            e0 = min(max(e0, 0), LL - 1);
            fsb[s0] = 1;                          // benign race: all write 1
            feb[e0] = 1;
        }
        __syncthreads();
        fsb[i0] = (i0 != 0 && fsb[i0] && mk0 == 1) ? 1 : 0;
        fsb[i1] = (fsb[i1] && mk1 == 1) ? 1 : 0;
        feb[i0] = (i0 != 0 && feb[i0]) ? 1 : 0;
        __syncthreads();

        for (int it = t; it < 64 * 5; it += 256) {
            const int s_loc = it / 5;
            const int slot  = it - s_loc * 5;     // 0..4
            const int s     = r0 + s_loc;
            const int offf  = b * NK + off_s(s);  // flat row start
            const int rowlen = (s <= S_LIN) ? (s + 11) : LL;
            const int p0 = ((((offf + s) >> 2) - 1 + slot) << 2);
            if (p0 < offf || p0 >= offf + rowlen) continue;   // not owner
            float vals[4];
            bool nonpure = false;
#pragma unroll
            for (int kk = 0; kk < 4; ++kk) {
                const int p = p0 + kk;
                float v = NEG_BIG;
                int rr, er;
                if (p < offf + rowlen) { rr = s;     er = p - offf; }
                else                   { rr = s + 1; er = p - offf - rowlen; }
                if (rr < LL) {
                    if (er >= rr) {               // tail position
                        nonpure = true;
                        if (fsb[rr] && feb[er]) {
                            float w = 0.f;
                            for (int l = rr; l <= er; ++l) w += ml[l];
                            v = sl[rr] + el[er] + w;
                            if (v < -1.0e29f) v = NEG_BIG;  // masked -> -inf
                        }
                    }
                } else {
                    nonpure = true;               // next batch row 0: invalid
                }
                vals[kk] = v;
            }
            if (nonpure) {
                f4v vv = {vals[0], vals[1], vals[2], vals[3]};
                *(f4v*)(out + p0) = vv;
            }
        }
        return;
    }

    if (id < TAILQ_CNT + MEMSET_CNT) {
        // ======== memset: write PURE quads only (R18 verbatim) ========
        const int gid = (id - TAILQ_CNT) * 256 + t;
        if (gid >= SC4) return;
        const int p4 = gid * 4;
        int b = p4 / NK;                          // magic-mul
        int k = p4 - b * NK;
        int s, e;
        invert(k, s, e);
        bool pure;
        if (e + 3 < s) {                          // fast path (~93%)
            pure = true;
        } else {
            pure = true;
            int ss = s, ee = e;
            int rowlen = (ss <= S_LIN) ? (ss + 11) : LL;
#pragma unroll
            for (int kk = 0; kk < 4; ++kk) {
                if (ee >= ss) { pure = false; break; }
                ++ee;
                if (ee >= rowlen) {
                    ee = 0; ++ss;
                    if (ss >= LL) ss = 0;         // next batch row 0
                    rowlen = (ss <= S_LIN) ? (ss + 11) : LL;
                }
            }
        }
        if (pure) {
            f4v neg = {NEG_BIG, NEG_BIG, NEG_BIG, NEG_BIG};
            *(f4v*)(out + p4) = neg;
        }
        return;
    }

    // ======== bounds: paired 16B stores, fan out to 16 batches (R19) ======
    const int q  = id - TAILQ_CNT - MEMSET_CNT;   // 0..BND_BLOCKS-1
    const int gg = (q >= BPG) ? 1 : 0;            // batch group
    const int c  = q - gg * BPG;
    const int pp = c * 256 + t;
    if (pp >= NP2) return;
    const int p0 = 2 * pp;
    int s0, e0; invert(p0, s0, e0);
    int s1 = s0, e1 = e0; adv(s1, e1);            // p0+1 (valid if p0+1<NK)
    int s2 = s1, e2 = e1; if (p0 + 2 < NK) adv(s2, e2);  // p0+2
    const float S0 = (float)s0, E0 = (float)e0;
    const float S1 = (float)s1, E1 = (float)e1;
    const float S2 = (float)s2, E2 = (float)e2;
    float* bp = out + (size_t)P_TOT;
#pragma unroll
    for (int j = 0; j < 16; ++j) {
        const int bb = gg * 16 + j;
        const size_t B = (size_t)bb * NK;
        if ((bb & 1) == 0) {                      // B even: (B+p0) even
            if (p0 + 1 < NK) {
                f4v vv = {S0, E0, S1, E1};
                *(f4v*)(bp + (B + p0) * 2) = vv;  // 16B aligned
            } else {
                f2v v2 = {S0, E0};
                *(f2v*)(bp + (B + p0) * 2) = v2;
            }
        } else {                                  // B odd: pairs (p0+1, p0+2)
            if (pp == 0) {                        // position 0: (s,e)=(0,0)
                f2v v2 = {0.f, 0.f};
                *(f2v*)(bp + B * 2) = v2;
            }
            if (p0 + 2 < NK) {
                f4v vv = {S1, E1, S2, E2};
                *(f4v*)(bp + (B + p0 + 1) * 2) = vv;  // (B+p0+1) even
            } else if (p0 + 1 < NK) {
                f2v v2 = {S1, E1};
                *(f2v*)(bp + (B + p0 + 1) * 2) = v2;
            }
        }
    }
}

extern "C" void kernel_launch(void* const* d_in, const int* in_sizes, int n_in,
                              void* d_out, int out_size, void* d_ws, size_t ws_size,
                              hipStream_t stream) {
    const float* text = (const float*)d_in[0];   // (B,L,D) f32
    const int*   mask = (const int*)d_in[1];     // (B,L) i32
    const int*   tmap = (const int*)d_in[2];     // (B,T,2) i32
    const float* W    = (const float*)d_in[3];   // (D,3) f32
    const float* bias = (const float*)d_in[4];   // (3,) f32
    float* out = (float*)d_out;

    float* slp = (float*)d_ws;                   // B*L each
    float* elp = slp + (size_t)BB * LL;
    float* mlp = elp + (size_t)BB * LL;

    gemv_kernel<<<GEMV_BLOCKS, 256, 0, stream>>>(text, W, bias, mask,
                                                 slp, elp, mlp);
    emit_kernel<<<D2_BLOCKS, 256, 0, stream>>>(slp, elp, mlp, mask, tmap, out);
}